// Round 1
// baseline (433.957 us; speedup 1.0000x reference)
//
#include <hip/hip_runtime.h>

// x: [B=4, C=8, H=128, W=128] f32 -> out: [B, C, 210, H*W] f32
// Channels 0..44   : v[i]*v[j],        i<=j       (pairs2 order)
// Channels 45..209 : v[i]*(v[j]*v[k]), i<=j<=k    (pairs3 order, matches ref assoc)

#define HH 128
#define WW 128
#define LL (HH * WW)
#define NCH 210

__global__ __launch_bounds__(256) void hoi_kernel(const float* __restrict__ x,
                                                  float* __restrict__ out) {
    const int tid   = blockIdx.x * 256 + threadIdx.x;
    const int wq    = tid & 31;          // which group of 4 columns
    const int h     = (tid >> 5) & 127;  // row
    const int plane = tid >> 12;         // b*C + c  (0..31)
    const int w0    = wq << 2;

    const float* __restrict__ xp = x + (size_t)plane * LL;

    // Load 3 rows x 6 cols neighborhood with zero padding.
    float r[3][6];
#pragma unroll
    for (int dh = 0; dh < 3; ++dh) {
        const int hh = h + dh - 1;
        const bool hv = (hh >= 0) & (hh < HH);
#pragma unroll
        for (int dw = 0; dw < 6; ++dw) {
            const int ww = w0 + dw - 1;
            const bool wv = (ww >= 0) & (ww < WW);
            r[dh][dw] = (hv & wv) ? xp[hh * WW + ww] : 0.0f;
        }
    }

    // 9 taps, each a float4 sliding window over the 4 pixels this thread owns.
    float4 v[9];
#pragma unroll
    for (int dh = 0; dh < 3; ++dh) {
#pragma unroll
        for (int dw = 0; dw < 3; ++dw) {
            v[dh * 3 + dw] = make_float4(r[dh][dw], r[dh][dw + 1],
                                         r[dh][dw + 2], r[dh][dw + 3]);
        }
    }

    float* __restrict__ obase = out + (size_t)plane * NCH * LL + h * WW + w0;
    int ch = 0;

    // Order-2: ht2 = v[i] * v[j], i <= j
#pragma unroll
    for (int i = 0; i < 9; ++i) {
#pragma unroll
        for (int j = i; j < 9; ++j) {
            float4 p;
            p.x = v[i].x * v[j].x;
            p.y = v[i].y * v[j].y;
            p.z = v[i].z * v[j].z;
            p.w = v[i].w * v[j].w;
            *reinterpret_cast<float4*>(obase + (size_t)ch * LL) = p;
            ++ch;
        }
    }

    // Order-3: ht3 = v[i] * (v[j] * v[k]), i <= j <= k  (matches ref: Col_i * ht2_jk)
#pragma unroll
    for (int i = 0; i < 9; ++i) {
#pragma unroll
        for (int j = i; j < 9; ++j) {
#pragma unroll
            for (int k = j; k < 9; ++k) {
                float4 q;
                q.x = v[i].x * (v[j].x * v[k].x);
                q.y = v[i].y * (v[j].y * v[k].y);
                q.z = v[i].z * (v[j].z * v[k].z);
                q.w = v[i].w * (v[j].w * v[k].w);
                *reinterpret_cast<float4*>(obase + (size_t)ch * LL) = q;
                ++ch;
            }
        }
    }
}

extern "C" void kernel_launch(void* const* d_in, const int* in_sizes, int n_in,
                              void* d_out, int out_size, void* d_ws, size_t ws_size,
                              hipStream_t stream) {
    const float* x = (const float*)d_in[0];
    float* out = (float*)d_out;

    const int nplanes = in_sizes[0] / LL;          // B*C = 32
    const int total   = nplanes * HH * (WW / 4);   // one thread per 4 pixels
    const int block   = 256;
    const int grid    = (total + block - 1) / block;

    hoi_kernel<<<grid, block, 0, stream>>>(x, out);
}

// Round 2
// 432.744 us; speedup vs baseline: 1.0028x; 1.0028x over previous
//
#include <hip/hip_runtime.h>

// x: [B=4, C=8, H=128, W=128] f32 -> out: [B, C, 210, H*W] f32
// Channels 0..44   : v[j]*v[k],        j<=k       (pairs2, i-major lex order)
// Channels 45..209 : v[i]*(v[j]*v[k]), i<=j<=k    (pairs3, i-major lex order)
//
// Emission is (j,k)-outer so each pair product t=v[j]*v[k] has a short live
// range: store t at ch2(j,k), then immediately emit v[i]*t for i=0..j at
// ch3(i,j,k). This kills the 45-float4-live-range CSE blowup of the i-major
// emission order (R1 post-mortem: suspected spill-bound at 1 TB/s).

#define HH 128
#define WW 128
#define LL (HH * WW)
#define NCH 210

__host__ __device__ constexpr int ch2_idx(int i, int j) {
    // pairs2 lex index, i <= j
    return i * 9 - (i * (i - 1)) / 2 + (j - i);
}
__host__ __device__ constexpr int tri(int m) { return m * (m + 1) / 2; }
__host__ __device__ constexpr int ch3_idx(int i, int j, int k) {
    // 45 + lex index of (i,j,k), i <= j <= k
    int s = 0;
    for (int a = 0; a < i; ++a) s += tri(9 - a);
    for (int b = i; b < j; ++b) s += (9 - b);
    return 45 + s + (k - j);
}

template <int JLO, int JHI>
__device__ __forceinline__ void emit(const float4 (&v)[9], float* __restrict__ obase) {
#pragma unroll
    for (int j = JLO; j < JHI; ++j) {
#pragma unroll
        for (int k = j; k < 9; ++k) {
            float4 t;
            t.x = v[j].x * v[k].x;
            t.y = v[j].y * v[k].y;
            t.z = v[j].z * v[k].z;
            t.w = v[j].w * v[k].w;
            *reinterpret_cast<float4*>(obase + ch2_idx(j, k) * LL) = t;
#pragma unroll
            for (int i = 0; i <= j; ++i) {
                float4 q;
                q.x = v[i].x * t.x;
                q.y = v[i].y * t.y;
                q.z = v[i].z * t.z;
                q.w = v[i].w * t.w;
                *reinterpret_cast<float4*>(obase + ch3_idx(i, j, k) * LL) = q;
            }
        }
    }
}

__global__ __launch_bounds__(256, 4) void hoi_kernel(const float* __restrict__ x,
                                                     float* __restrict__ out) {
    const int tid   = blockIdx.x * 256 + threadIdx.x;
    const int wq    = tid & 31;          // group of 4 columns
    const int h     = (tid >> 5) & 127;  // row
    const int plane = tid >> 12;         // b*C + c  (0..31)
    const int w0    = wq << 2;

    const float* __restrict__ xp = x + (size_t)plane * LL;

    // 3 rows x 6 cols neighborhood, zero-padded.
    float r[3][6];
#pragma unroll
    for (int dh = 0; dh < 3; ++dh) {
        const int hh = h + dh - 1;
        const bool hv = (hh >= 0) & (hh < HH);
#pragma unroll
        for (int dw = 0; dw < 6; ++dw) {
            const int ww = w0 + dw - 1;
            const bool wv = (ww >= 0) & (ww < WW);
            r[dh][dw] = (hv & wv) ? xp[hh * WW + ww] : 0.0f;
        }
    }

    // 9 taps, each a float4 sliding window over this thread's 4 pixels.
    float4 v[9];
#pragma unroll
    for (int dh = 0; dh < 3; ++dh) {
#pragma unroll
        for (int dw = 0; dw < 3; ++dw) {
            v[dh * 3 + dw] = make_float4(r[dh][dw], r[dh][dw + 1],
                                         r[dh][dw + 2], r[dh][dw + 3]);
        }
    }

    float* __restrict__ obase = out + (size_t)plane * NCH * LL + h * WW + w0;

    // Channel split across gridDim.y: j<4 -> 100 stores, j>=4 -> 110 stores.
    if (blockIdx.y == 0) {
        emit<0, 4>(v, obase);
    } else {
        emit<4, 9>(v, obase);
    }
}

extern "C" void kernel_launch(void* const* d_in, const int* in_sizes, int n_in,
                              void* d_out, int out_size, void* d_ws, size_t ws_size,
                              hipStream_t stream) {
    const float* x = (const float*)d_in[0];
    float* out = (float*)d_out;

    const int nplanes = in_sizes[0] / LL;          // B*C = 32
    const int total   = nplanes * HH * (WW / 4);   // one thread per 4 pixels
    const int block   = 256;
    const int gx      = (total + block - 1) / block;

    hoi_kernel<<<dim3(gx, 2), block, 0, stream>>>(x, out);
}